// Round 1
// baseline (1173.493 us; speedup 1.0000x reference)
//
#include <hip/hip_runtime.h>

#define C 128
#define DD 256
#define NOUT 2
#define ALPHA 0.1f
#define SLOPE 0.01f

// ---------------- graph preprocessing ----------------

__global__ void count_kernel(const int* __restrict__ col, int* __restrict__ cnt, int E) {
    int e = blockIdx.x * 256 + threadIdx.x;
    if (e < E) atomicAdd(&cnt[col[e]], 1);
}

__global__ void dinv_kernel(const int* __restrict__ cnt, float* __restrict__ dinv, int n) {
    int i = blockIdx.x * 256 + threadIdx.x;
    if (i < n) dinv[i] = rsqrtf((float)(cnt[i] + 1));   // +1 self-loop; always > 0
}

// single-block exclusive scan over n (~50K) elements
__global__ void scan_kernel(const int* __restrict__ cnt, int* __restrict__ offs, int n) {
    __shared__ int lds[1024];
    __shared__ int carry;
    if (threadIdx.x == 0) carry = 0;
    __syncthreads();
    for (int base = 0; base < n; base += 1024) {
        int i = base + (int)threadIdx.x;
        int v = (i < n) ? cnt[i] : 0;
        lds[threadIdx.x] = v;
        __syncthreads();
        for (int off = 1; off < 1024; off <<= 1) {
            int t = (threadIdx.x >= off) ? lds[threadIdx.x - off] : 0;
            __syncthreads();
            lds[threadIdx.x] += t;
            __syncthreads();
        }
        int incl = lds[threadIdx.x];
        if (i < n) offs[i] = carry + incl - v;   // exclusive
        __syncthreads();
        if (threadIdx.x == 1023) carry += incl;  // chunk total
        __syncthreads();
    }
    if (threadIdx.x == 0) offs[n] = carry;
}

__global__ void copy_kernel(const int* __restrict__ src, int* __restrict__ dst, int n) {
    int i = blockIdx.x * 256 + threadIdx.x;
    if (i < n) dst[i] = src[i];
}

__global__ void fill_kernel(const int* __restrict__ row, const int* __restrict__ col,
                            const float* __restrict__ dinv, int* __restrict__ cursor,
                            int* __restrict__ csr_src, float* __restrict__ csr_nrm, int E) {
    int e = blockIdx.x * 256 + threadIdx.x;
    if (e >= E) return;
    int r = row[e], c = col[e];
    int pos = atomicAdd(&cursor[c], 1);
    csr_src[pos] = r;
    csr_nrm[pos] = dinv[r] * dinv[c];
}

// ---------------- fused GCN2 layer: gather + residual + GEMM + LeakyReLU ----------------
// one block per node; 128 threads = 128 channels
__global__ __launch_bounds__(C) void layer_kernel(
    const float* __restrict__ xc, const float* __restrict__ x0,
    const float* __restrict__ W, const int* __restrict__ offs,
    const int* __restrict__ csr_src, const float* __restrict__ csr_nrm,
    const float* __restrict__ dinv, float* __restrict__ xn, int n)
{
    __shared__ float z[C];
    int i = blockIdx.x;
    if (i >= n) return;
    int c = threadIdx.x;

    int beg = offs[i], end = offs[i + 1];
    float acc = 0.f;
    for (int k = beg; k < end; ++k) {
        int s = csr_src[k];
        float w = csr_nrm[k];
        acc += w * xc[(size_t)s * C + c];
    }
    float di = dinv[i];
    float h = acc + di * di * xc[(size_t)i * C + c];          // self-loop term
    float zz = (1.0f - ALPHA) * h + ALPHA * x0[(size_t)i * C + c];
    z[c] = zz;
    __syncthreads();

    float y = 0.f;
    #pragma unroll 8
    for (int k = 0; k < C; ++k) y += z[k] * W[k * C + c];
    y = (y > 0.f) ? y : SLOPE * y;
    xn[(size_t)i * C + c] = y;
}

// ---------------- dense head: 128 -> 256 -> 2 ----------------
__global__ __launch_bounds__(DD) void dense_kernel(
    const float* __restrict__ xin, const float* __restrict__ wd, const float* __restrict__ bd,
    const float* __restrict__ wo, const float* __restrict__ bo, float* __restrict__ out, int n)
{
    __shared__ float xr[C];
    __shared__ float hid[DD];
    int i = blockIdx.x;
    if (i >= n) return;
    int t = threadIdx.x;
    if (t < C) xr[t] = xin[(size_t)i * C + t];
    __syncthreads();

    float acc = bd[t];
    #pragma unroll 8
    for (int c = 0; c < C; ++c) acc += xr[c] * wd[c * DD + t];
    hid[t] = acc;
    __syncthreads();

    int w = t >> 6, l = t & 63;
    if (w < NOUT) {
        float p = 0.f;
        for (int d = l; d < DD; d += 64) p += hid[d] * wo[d * NOUT + w];
        for (int off = 32; off; off >>= 1) p += __shfl_down(p, off);
        if (l == 0) out[(size_t)i * NOUT + w] = bo[w] + p;
    }
}

extern "C" void kernel_launch(void* const* d_in, const int* in_sizes, int n_in,
                              void* d_out, int out_size, void* d_ws, size_t ws_size,
                              hipStream_t stream) {
    const float* x0    = (const float*)d_in[0];
    const int*   ei    = (const int*)d_in[1];
    const float* convW = (const float*)d_in[2];
    const float* wd    = (const float*)d_in[3];
    const float* bd    = (const float*)d_in[4];
    const float* wo    = (const float*)d_in[5];
    const float* bo    = (const float*)d_in[6];
    float* out = (float*)d_out;

    int N = in_sizes[0] / C;
    int E = in_sizes[1] / 2;
    int L = in_sizes[2] / (C * C);
    const int* row = ei;
    const int* col = ei + E;

    char* p = (char*)d_ws;
    auto alloc = [&](size_t bytes) {
        char* r = p;
        p += (bytes + 255) & ~(size_t)255;
        return r;
    };
    int*   cnt     = (int*)alloc((size_t)N * 4);
    int*   offs    = (int*)alloc((size_t)(N + 1) * 4);
    int*   cursor  = (int*)alloc((size_t)N * 4);
    int*   csr_src = (int*)alloc((size_t)E * 4);
    float* csr_nrm = (float*)alloc((size_t)E * 4);
    float* dinv    = (float*)alloc((size_t)N * 4);
    float* bufA    = (float*)alloc((size_t)N * C * 4);
    float* bufB    = (float*)alloc((size_t)N * C * 4);

    hipMemsetAsync(cnt, 0, (size_t)N * 4, stream);
    count_kernel<<<(E + 255) / 256, 256, 0, stream>>>(col, cnt, E);
    dinv_kernel<<<(N + 255) / 256, 256, 0, stream>>>(cnt, dinv, N);
    scan_kernel<<<1, 1024, 0, stream>>>(cnt, offs, N);
    copy_kernel<<<(N + 255) / 256, 256, 0, stream>>>(offs, cursor, N);
    fill_kernel<<<(E + 255) / 256, 256, 0, stream>>>(row, col, dinv, cursor, csr_src, csr_nrm, E);

    const float* xc = x0;
    float* xn = bufA;
    for (int l = 0; l < L; ++l) {
        layer_kernel<<<N, C, 0, stream>>>(xc, x0, convW + (size_t)l * C * C,
                                          offs, csr_src, csr_nrm, dinv, xn, N);
        xc = xn;
        xn = (xn == bufA) ? bufB : bufA;
    }
    dense_kernel<<<N, DD, 0, stream>>>(xc, wd, bd, wo, bo, out, N);
}

// Round 2
// 678.067 us; speedup vs baseline: 1.7306x; 1.7306x over previous
//
#include <hip/hip_runtime.h>

#define C 128
#define DD 256
#define NOUT 2
#define ALPHA 0.1f
#define SLOPE 0.01f
#define ZSTR 132   // padded LDS row stride (floats), 16B-aligned

// ---------------- graph preprocessing ----------------

__global__ void count_kernel(const int* __restrict__ col, int* __restrict__ cnt, int E) {
    int e = blockIdx.x * 256 + threadIdx.x;
    if (e < E) atomicAdd(&cnt[col[e]], 1);
}

__global__ void dinv_kernel(const int* __restrict__ cnt, float* __restrict__ dinv, int n) {
    int i = blockIdx.x * 256 + threadIdx.x;
    if (i < n) dinv[i] = rsqrtf((float)(cnt[i] + 1));   // +1 self-loop; always > 0
}

// single-block exclusive scan: 1024 threads, 4 elems/thread, shuffle-based
__global__ __launch_bounds__(1024) void scan_kernel(const int* __restrict__ cnt,
                                                    int* __restrict__ offs, int n) {
    __shared__ int wsum[16];
    __shared__ int chunk_carry;
    int t = threadIdx.x;
    int lane = t & 63, wv = t >> 6;
    if (t == 0) chunk_carry = 0;
    __syncthreads();
    for (int base = 0; base < n; base += 4096) {
        int idx = base + t * 4;
        int v0 = (idx + 0 < n) ? cnt[idx + 0] : 0;
        int v1 = (idx + 1 < n) ? cnt[idx + 1] : 0;
        int v2 = (idx + 2 < n) ? cnt[idx + 2] : 0;
        int v3 = (idx + 3 < n) ? cnt[idx + 3] : 0;
        int s0 = v0, s1 = s0 + v1, s2 = s1 + v2, s3 = s2 + v3;
        int tot = s3;
        int sc = tot;                       // inclusive wave scan
        #pragma unroll
        for (int d = 1; d < 64; d <<= 1) {
            int u = __shfl_up(sc, d);
            if (lane >= d) sc += u;
        }
        if (lane == 63) wsum[wv] = sc;
        __syncthreads();
        int woff = 0;
        #pragma unroll
        for (int j = 0; j < 16; ++j) woff += (j < wv) ? wsum[j] : 0;
        int excl = chunk_carry + woff + (sc - tot);
        if (idx + 0 < n) offs[idx + 0] = excl;
        if (idx + 1 < n) offs[idx + 1] = excl + s0;
        if (idx + 2 < n) offs[idx + 2] = excl + s1;
        if (idx + 3 < n) offs[idx + 3] = excl + s2;
        __syncthreads();                     // all done reading chunk_carry/wsum
        if (t == 1023) chunk_carry = excl + s3;
        __syncthreads();                     // update visible
    }
    if (t == 0) offs[n] = chunk_carry;
}

__global__ void copy_kernel(const int* __restrict__ src, int* __restrict__ dst, int n) {
    int i = blockIdx.x * 256 + threadIdx.x;
    if (i < n) dst[i] = src[i];
}

__global__ void fill_kernel(const int* __restrict__ row, const int* __restrict__ col,
                            const float* __restrict__ dinv, int* __restrict__ cursor,
                            int* __restrict__ csr_src, float* __restrict__ csr_nrm, int E) {
    int e = blockIdx.x * 256 + threadIdx.x;
    if (e >= E) return;
    int r = row[e], c = col[e];
    int pos = atomicAdd(&cursor[c], 1);
    csr_src[pos] = r;
    csr_nrm[pos] = dinv[r] * dinv[c];
}

// ---------------- aggregation: h[i] = sum_j norm*x[j] + dinv(i)^2 * x[i] ----------------
// one block per node; 128 threads = 32 float4-lanes x 4 edge slots
__global__ __launch_bounds__(128) void agg_kernel(
    const float* __restrict__ xc, const int* __restrict__ offs,
    const int* __restrict__ csr_src, const float* __restrict__ csr_nrm,
    const float* __restrict__ dinv, float* __restrict__ h, int n)
{
    __shared__ float4 part[4][32];
    int i = blockIdx.x;
    int t = threadIdx.x;
    int lane = t & 31;       // float4 slot within row
    int s = t >> 5;          // edge slot 0..3
    int beg = offs[i], end = offs[i + 1];
    const float4* x4 = (const float4*)xc;
    float4 acc = {0.f, 0.f, 0.f, 0.f};
    for (int k = beg + s; k < end; k += 4) {
        int src = csr_src[k];
        float w = csr_nrm[k];
        float4 v = x4[(size_t)src * 32 + lane];
        acc.x += w * v.x; acc.y += w * v.y; acc.z += w * v.z; acc.w += w * v.w;
    }
    part[s][lane] = acc;
    __syncthreads();
    if (s == 0) {
        float4 a = part[0][lane], b = part[1][lane], c2 = part[2][lane], d = part[3][lane];
        float di = dinv[i];
        float w0 = di * di;
        float4 self = x4[(size_t)i * 32 + lane];
        float4 r;
        r.x = a.x + b.x + c2.x + d.x + w0 * self.x;
        r.y = a.y + b.y + c2.y + d.y + w0 * self.y;
        r.z = a.z + b.z + c2.z + d.z + w0 * self.z;
        r.w = a.w + b.w + c2.w + d.w + w0 * self.w;
        ((float4*)h)[(size_t)i * 32 + lane] = r;
    }
}

// ---------------- layer GEMM: xn = leaky(((1-a)h + a*x0) @ W), in-place safe (xn may == h)
// 256 threads, 64 nodes/block; thread = (col-group t&31 -> 4 cols, node-group t>>5 -> 8 nodes)
__global__ __launch_bounds__(256) void layer_gemm(
    const float* __restrict__ h, const float* __restrict__ x0,
    const float* __restrict__ W, float* __restrict__ xn, int n)
{
    __shared__ float z[64 * ZSTR];
    int i0 = blockIdx.x * 64;
    int t = threadIdx.x;
    // stage z tile
    for (int p = t; p < 64 * 32; p += 256) {
        int r = p >> 5, c4 = p & 31;
        float4 zv = {0.f, 0.f, 0.f, 0.f};
        if (i0 + r < n) {
            size_t gi = (size_t)(i0 + r) * 32 + c4;
            float4 hv = ((const float4*)h)[gi];
            float4 xv = ((const float4*)x0)[gi];
            zv.x = (1.f - ALPHA) * hv.x + ALPHA * xv.x;
            zv.y = (1.f - ALPHA) * hv.y + ALPHA * xv.y;
            zv.z = (1.f - ALPHA) * hv.z + ALPHA * xv.z;
            zv.w = (1.f - ALPHA) * hv.w + ALPHA * xv.w;
        }
        *(float4*)&z[r * ZSTR + c4 * 4] = zv;
    }
    __syncthreads();

    int cl = t & 31;    // cols 4*cl..4*cl+3
    int ng = t >> 5;    // nodes ng*8..ng*8+7
    float4 acc[8] = {};
    const float4* W4 = (const float4*)W;
    float4 w0 = W4[0 * 32 + cl], w1 = W4[1 * 32 + cl];
    float4 w2 = W4[2 * 32 + cl], w3 = W4[3 * 32 + cl];
    for (int k = 0; k < C; k += 4) {
        int kn = (k + 4) & 127;     // wrap avoids OOB; redundant load at tail
        float4 nw0 = W4[(kn + 0) * 32 + cl];
        float4 nw1 = W4[(kn + 1) * 32 + cl];
        float4 nw2 = W4[(kn + 2) * 32 + cl];
        float4 nw3 = W4[(kn + 3) * 32 + cl];
        #pragma unroll
        for (int nj = 0; nj < 8; ++nj) {
            float4 zv = *(const float4*)&z[(ng * 8 + nj) * ZSTR + k];
            acc[nj].x += zv.x * w0.x + zv.y * w1.x + zv.z * w2.x + zv.w * w3.x;
            acc[nj].y += zv.x * w0.y + zv.y * w1.y + zv.z * w2.y + zv.w * w3.y;
            acc[nj].z += zv.x * w0.z + zv.y * w1.z + zv.z * w2.z + zv.w * w3.z;
            acc[nj].w += zv.x * w0.w + zv.y * w1.w + zv.z * w2.w + zv.w * w3.w;
        }
        w0 = nw0; w1 = nw1; w2 = nw2; w3 = nw3;
    }
    #pragma unroll
    for (int nj = 0; nj < 8; ++nj) {
        int node = i0 + ng * 8 + nj;
        if (node < n) {
            float4 a = acc[nj];
            a.x = a.x > 0.f ? a.x : SLOPE * a.x;
            a.y = a.y > 0.f ? a.y : SLOPE * a.y;
            a.z = a.z > 0.f ? a.z : SLOPE * a.z;
            a.w = a.w > 0.f ? a.w : SLOPE * a.w;
            ((float4*)xn)[(size_t)node * 32 + cl] = a;
        }
    }
}

// ---------------- dense head: out = (x@wd + bd) @ wo + bo ----------------
// 256 threads, 32 nodes/block; thread = (col-group t&63 -> 4 of 256 cols, wave t>>6 -> 8 nodes)
__global__ __launch_bounds__(256) void dense_gemm(
    const float* __restrict__ xin, const float* __restrict__ wd, const float* __restrict__ bd,
    const float* __restrict__ wo, const float* __restrict__ bo, float* __restrict__ out, int n)
{
    __shared__ float xr[32 * ZSTR];
    int i0 = blockIdx.x * 32;
    int t = threadIdx.x;
    for (int p = t; p < 32 * 32; p += 256) {
        int r = p >> 5, c4 = p & 31;
        float4 v = {0.f, 0.f, 0.f, 0.f};
        if (i0 + r < n) v = ((const float4*)xin)[(size_t)(i0 + r) * 32 + c4];
        *(float4*)&xr[r * ZSTR + c4 * 4] = v;
    }
    __syncthreads();

    int cl = t & 63;    // cols 4*cl..4*cl+3 of 256
    int w = t >> 6;     // wave id; nodes w*8..w*8+7
    float4 acc[8] = {};
    const float4* wd4 = (const float4*)wd;
    float4 w0 = wd4[0 * 64 + cl], w1 = wd4[1 * 64 + cl];
    float4 w2 = wd4[2 * 64 + cl], w3 = wd4[3 * 64 + cl];
    for (int k = 0; k < C; k += 4) {
        int kn = (k + 4) & 127;
        float4 nw0 = wd4[(kn + 0) * 64 + cl];
        float4 nw1 = wd4[(kn + 1) * 64 + cl];
        float4 nw2 = wd4[(kn + 2) * 64 + cl];
        float4 nw3 = wd4[(kn + 3) * 64 + cl];
        #pragma unroll
        for (int nj = 0; nj < 8; ++nj) {
            float4 xv = *(const float4*)&xr[(w * 8 + nj) * ZSTR + k];
            acc[nj].x += xv.x * w0.x + xv.y * w1.x + xv.z * w2.x + xv.w * w3.x;
            acc[nj].y += xv.x * w0.y + xv.y * w1.y + xv.z * w2.y + xv.w * w3.y;
            acc[nj].z += xv.x * w0.z + xv.y * w1.z + xv.z * w2.z + xv.w * w3.z;
            acc[nj].w += xv.x * w0.w + xv.y * w1.w + xv.z * w2.w + xv.w * w3.w;
        }
        w0 = nw0; w1 = nw1; w2 = nw2; w3 = nw3;
    }
    // second GEMM (256 -> 2) + wave reduction
    float4 bdv = ((const float4*)bd)[cl];
    const float4* wo4 = (const float4*)wo;
    float4 woa = wo4[cl * 2 + 0];   // wo[4cl+0][0], wo[4cl+0][1], wo[4cl+1][0], wo[4cl+1][1]
    float4 wob = wo4[cl * 2 + 1];   // wo[4cl+2][0], wo[4cl+2][1], wo[4cl+3][0], wo[4cl+3][1]
    float bo0 = bo[0], bo1 = bo[1];
    #pragma unroll
    for (int nj = 0; nj < 8; ++nj) {
        float4 hid;
        hid.x = acc[nj].x + bdv.x;
        hid.y = acc[nj].y + bdv.y;
        hid.z = acc[nj].z + bdv.z;
        hid.w = acc[nj].w + bdv.w;
        float p0 = hid.x * woa.x + hid.y * woa.z + hid.z * wob.x + hid.w * wob.z;
        float p1 = hid.x * woa.y + hid.y * woa.w + hid.z * wob.y + hid.w * wob.w;
        #pragma unroll
        for (int off = 32; off; off >>= 1) {
            p0 += __shfl_down(p0, off);
            p1 += __shfl_down(p1, off);
        }
        int node = i0 + w * 8 + nj;
        if (cl == 0 && node < n) {
            out[(size_t)node * NOUT + 0] = bo0 + p0;
            out[(size_t)node * NOUT + 1] = bo1 + p1;
        }
    }
}

extern "C" void kernel_launch(void* const* d_in, const int* in_sizes, int n_in,
                              void* d_out, int out_size, void* d_ws, size_t ws_size,
                              hipStream_t stream) {
    const float* x0    = (const float*)d_in[0];
    const int*   ei    = (const int*)d_in[1];
    const float* convW = (const float*)d_in[2];
    const float* wd    = (const float*)d_in[3];
    const float* bd    = (const float*)d_in[4];
    const float* wo    = (const float*)d_in[5];
    const float* bo    = (const float*)d_in[6];
    float* out = (float*)d_out;

    int N = in_sizes[0] / C;
    int E = in_sizes[1] / 2;
    int L = in_sizes[2] / (C * C);
    const int* row = ei;
    const int* col = ei + E;

    char* p = (char*)d_ws;
    auto alloc = [&](size_t bytes) {
        char* r = p;
        p += (bytes + 255) & ~(size_t)255;
        return r;
    };
    int*   cnt     = (int*)alloc((size_t)N * 4);
    int*   offs    = (int*)alloc((size_t)(N + 1) * 4);
    int*   cursor  = (int*)alloc((size_t)N * 4);
    int*   csr_src = (int*)alloc((size_t)E * 4);
    float* csr_nrm = (float*)alloc((size_t)E * 4);
    float* dinv    = (float*)alloc((size_t)N * 4);
    float* bufA    = (float*)alloc((size_t)N * C * 4);
    float* bufB    = (float*)alloc((size_t)N * C * 4);

    hipMemsetAsync(cnt, 0, (size_t)N * 4, stream);
    count_kernel<<<(E + 255) / 256, 256, 0, stream>>>(col, cnt, E);
    dinv_kernel<<<(N + 255) / 256, 256, 0, stream>>>(cnt, dinv, N);
    scan_kernel<<<1, 1024, 0, stream>>>(cnt, offs, N);
    copy_kernel<<<(N + 255) / 256, 256, 0, stream>>>(offs, cursor, N);
    fill_kernel<<<(E + 255) / 256, 256, 0, stream>>>(row, col, dinv, cursor, csr_src, csr_nrm, E);

    const float* xc = x0;
    for (int l = 0; l < L; ++l) {
        float* hbuf = (l & 1) ? bufB : bufA;
        agg_kernel<<<N, 128, 0, stream>>>(xc, offs, csr_src, csr_nrm, dinv, hbuf, N);
        layer_gemm<<<(N + 63) / 64, 256, 0, stream>>>(hbuf, x0, convW + (size_t)l * C * C,
                                                      hbuf, N);   // in-place: block reads its rows into LDS first
        xc = hbuf;
    }
    dense_gemm<<<(N + 31) / 32, 256, 0, stream>>>(xc, wd, bd, wo, bo, out, N);
}